// Round 17
// baseline (363.951 us; speedup 1.0000x reference)
//
#include <hip/hip_runtime.h>
#include <math.h>

typedef _Float16 f16;
typedef f16 f16x8 __attribute__((ext_vector_type(8)));
typedef float f32x16 __attribute__((ext_vector_type(16)));
typedef unsigned short u16;
typedef unsigned int u32;
typedef unsigned long long u64;
typedef u32 u32x4 __attribute__((ext_vector_type(4)));

#define B_ 2
#define C_ 64
#define KS 5              // 64 feats + bias(k=64) + zero pad
#define H_ 112
#define W_ 112
#define N_ 12544
#define S_ 50
#define G_ 120
#define SPLIT 8
#define LCAP 4
#define CPR (SPLIT*2*LCAP)  // 64 candidates per compacted row
#define TMAX 400            // allocated tiles per batch (>= ceil(12608/32))
#define CMAPN 12800         // compacted-slot map capacity per batch

#define NEGINF (-__builtin_inff())
#define FMED3 __builtin_amdgcn_fmed3f

union U16B { uint4 u; f16x8 h; f16 e[8]; };

// hdr layout: [0]=flag1 [1]=flag2 [2..3]=cntY[b] [4..5]=cntX[b]
//             [6..7]=MYpad[b] (mult 256)  [8..9]=NXpad[b] (mult 64)

// ---------------------------------------------------------------------------
// Kernel 0: mask format detect (byte vs int32) + zero the compaction counters.
// ---------------------------------------------------------------------------
__global__ void detect_fmt(const u32* __restrict__ m1, const u32* __restrict__ m2,
                           int nw, int* __restrict__ hdr) {
    __shared__ u32 s[2];
    if (threadIdx.x == 0) { s[0] = 0; s[1] = 0; }
    __syncthreads();
    u32 a = 0, bb = 0;
    for (int i = threadIdx.x; i < nw; i += blockDim.x) {
        a  |= m1[i] & 0xFFFFFF00u;
        bb |= m2[i] & 0xFFFFFF00u;
    }
    if (a)  atomicOr(&s[0], 1u);
    if (bb) atomicOr(&s[1], 1u);
    __syncthreads();
    if (threadIdx.x == 0) {
        hdr[0] = s[0] ? 1 : 0; hdr[1] = s[1] ? 1 : 0;
        hdr[2] = 0; hdr[3] = 0; hdr[4] = 0; hdr[5] = 0;
        hdr[6] = 0; hdr[7] = 0; hdr[8] = 0; hdr[9] = 0;
    }
}

// ---------------------------------------------------------------------------
// Kernel 1 (fused, with compaction):
// y==0 (src/x): write fxT (orig idx). Invalid rows -> out = -1 prefill.
//   Valid rows -> atomic slot, cmapX, fxq frags at COMPACTED col
//   (k<64: v; k==64: 1.0 bias partner; else 0).
// y==1 (dst/y): fynT/nyeps/minf at orig idx (round-1 arithmetic). Valid rows
//   -> atomic slot, cmapY, fynq frags at COMPACTED row
//   (k<64: v/ny; k==64: 128.0 bias -> all scores positive; else 0).
// Masked dst rows simply don't exist in fynq (== -inf ranking in reference).
// ---------------------------------------------------------------------------
__global__ void prep(const float* __restrict__ fx, const float* __restrict__ fy,
                     const unsigned char* __restrict__ mask1b,
                     const unsigned char* __restrict__ mask2b,
                     int* __restrict__ hdr,
                     f16* __restrict__ fxq, float* __restrict__ fxT,
                     float* __restrict__ fynT, f16* __restrict__ fynq,
                     float* __restrict__ nyeps, float* __restrict__ minf,
                     int* __restrict__ cmapX, int* __restrict__ cmapY,
                     float* __restrict__ out) {
    int t = blockIdx.x * blockDim.x + threadIdx.x;   // t = b*N + pixel
    if (t >= B_ * N_) return;
    int b = t / N_, m = t - b * N_;

    if (blockIdx.y == 0) {
        const float* src = fx + (size_t)b * C_ * N_ + m;
        float v[64];
        #pragma unroll
        for (int c = 0; c < C_; ++c) v[c] = src[(size_t)c * N_];

        float4* xT = (float4*)(fxT + (size_t)t * C_);
        #pragma unroll
        for (int c4 = 0; c4 < 16; ++c4)
            xT[c4] = make_float4(v[c4*4], v[c4*4+1], v[c4*4+2], v[c4*4+3]);

        bool valid = hdr[0] ? (mask1b[t] != 0) : (((const int*)mask1b)[t] != 0);
        if (!valid) {
            out[2 * (size_t)t] = -1.0f;
            out[2 * (size_t)t + 1] = -1.0f;
            return;
        }
        int slot = atomicAdd(&hdr[4 + b], 1);
        cmapX[b * CMAPN + slot] = m;
        int tile = slot >> 5, r = slot & 31;
        uint4* q4 = (uint4*)fxq;
        size_t cb = (size_t)(b * TMAX + tile) * (KS * 64);
        #pragma unroll
        for (int ks = 0; ks < KS; ++ks) {
            #pragma unroll
            for (int hi = 0; hi < 2; ++hi) {
                U16B tmp;
                #pragma unroll
                for (int i = 0; i < 8; ++i) {
                    int k = 16 * ks + 8 * hi + i;
                    float val = (k < 64) ? v[k] : ((k == 64) ? 1.0f : 0.0f);
                    tmp.e[i] = (f16)val;
                }
                q4[cb + (size_t)ks * 64 + hi * 32 + r] = tmp.u;
            }
        }
    } else {
        const float* src = fy + (size_t)b * C_ * N_ + m;
        float v[64];
        float ss = 0.f;
        #pragma unroll
        for (int c = 0; c < C_; ++c) { v[c] = src[(size_t)c * N_]; ss = fmaf(v[c], v[c], ss); }
        float ny = sqrtf(ss) + 1e-12f;
        nyeps[t] = ny;
        bool valid = hdr[1] ? (mask2b[t] != 0) : (((const int*)mask2b)[t] != 0);
        minf[t] = valid ? 0.0f : NEGINF;

        float* dT = fynT + (size_t)t * C_;
        #pragma unroll
        for (int c = 0; c < C_; ++c) dT[c] = v[c] / ny;   // round-1 arithmetic

        if (!valid) return;
        int slot = atomicAdd(&hdr[2 + b], 1);
        cmapY[b * CMAPN + slot] = m;
        int tile = slot >> 5, r = slot & 31;
        uint4* q4 = (uint4*)fynq;
        size_t cb = (size_t)(b * TMAX + tile) * (KS * 64);
        #pragma unroll
        for (int ks = 0; ks < KS; ++ks) {
            #pragma unroll
            for (int hi = 0; hi < 2; ++hi) {
                U16B tmp;
                #pragma unroll
                for (int i = 0; i < 8; ++i) {
                    int k = 16 * ks + 8 * hi + i;
                    float val = (k < 64) ? (v[k] / ny) : ((k == 64) ? 128.0f : 0.0f);
                    tmp.e[i] = (f16)val;
                }
                q4[cb + (size_t)ks * 64 + hi * 32 + r] = tmp.u;
            }
        }
    }
}

// ---------------------------------------------------------------------------
// Kernel 1b: compute padded sizes; zero-fill pad rows/cols (score ~0, real
// scores ~128 -> pads never become candidates) and pad cmap entries -> 0.
// ---------------------------------------------------------------------------
__global__ void padfill(int* __restrict__ hdr, uint4* __restrict__ fynq4,
                        uint4* __restrict__ fxq4, int* __restrict__ cmapY,
                        int* __restrict__ cmapX) {
    int tid = threadIdx.x;
    __shared__ int sMY[2], sNX[2], sCY[2], sCX[2];
    if (tid == 0) {
        for (int b = 0; b < B_; ++b) {
            int cy = hdr[2 + b], cx = hdr[4 + b];
            int my = (cy + 255) & ~255;
            int nx = (cx + 63) & ~63;
            hdr[6 + b] = my; hdr[8 + b] = nx;
            sMY[b] = my; sNX[b] = nx; sCY[b] = cy; sCX[b] = cx;
        }
    }
    __syncthreads();
    uint4 z = make_uint4(0, 0, 0, 0);
    for (int b = 0; b < B_; ++b) {
        for (int p = sCY[b] + tid; p < sMY[b]; p += blockDim.x) {
            cmapY[b * CMAPN + p] = 0;
            int tile = p >> 5, r = p & 31;
            size_t cb = (size_t)(b * TMAX + tile) * (KS * 64);
            #pragma unroll
            for (int ks = 0; ks < KS; ++ks) {
                fynq4[cb + (size_t)ks * 64 + r] = z;
                fynq4[cb + (size_t)ks * 64 + 32 + r] = z;
            }
        }
        for (int p = sCX[b] + tid; p < sNX[b]; p += blockDim.x) {
            cmapX[b * CMAPN + p] = 0;
            int tile = p >> 5, r = p & 31;
            size_t cb = (size_t)(b * TMAX + tile) * (KS * 64);
            #pragma unroll
            for (int ks = 0; ks < KS; ++ks) {
                fxq4[cb + (size_t)ks * 64 + r] = z;
                fxq4[cb + (size_t)ks * 64 + 32 + r] = z;
            }
        }
    }
}

// ---------------------------------------------------------------------------
// Kernel 2: MFMA candidate pass on COMPACTED matrices (~1/4 the cells).
// R16 inner structure (best measured). Runtime loop bound TPSr = MYpad/256
// per split; per-wave exit for pad cols. 10-bit (tile*16+reg) index packed
// into mantissa low bits; med3 chain = exact top-4 per lane-half stream.
// ---------------------------------------------------------------------------
#define LDA(dst, t) { _Pragma("unroll") \
    for (int ks = 0; ks < KS; ++ks) \
        dst[ks] = fyb8[((size_t)(t) * KS + ks) * 64]; }

#define MFMAC(acc, a) { \
    acc = __builtin_amdgcn_mfma_f32_32x32x16_f16(a[0], bfr[0], zvec, 0, 0, 0); \
    acc = __builtin_amdgcn_mfma_f32_32x32x16_f16(a[1], bfr[1], acc, 0, 0, 0); \
    acc = __builtin_amdgcn_mfma_f32_32x32x16_f16(a[2], bfr[2], acc, 0, 0, 0); \
    acc = __builtin_amdgcn_mfma_f32_32x32x16_f16(a[3], bfr[3], acc, 0, 0, 0); \
    acc = __builtin_amdgcn_mfma_f32_32x32x16_f16(a[4], bfr[4], acc, 0, 0, 0); }

#define EXTRACT(acc, bse) { \
    _Pragma("unroll") \
    for (int r = 0; r < 16; ++r) { \
        u32 pb_ = (__float_as_uint(acc[r]) & VMASK) | ((bse) + (u32)r); \
        float p_ = __uint_as_float(pb_); \
        b4 = FMED3(p_, b3, b4); \
        b3 = FMED3(p_, b2, b3); \
        b2 = FMED3(p_, b1, b2); \
        b1 = fmaxf(p_, b1); } }

#define CELL(a, t) { f32x16 acc_; MFMAC(acc_, a); EXTRACT(acc_, (u32)((t) * 16)); }

__global__ __launch_bounds__(128, 4)
void stage1(const f16* __restrict__ fxq, const f16* __restrict__ fynq,
            const int* __restrict__ hdr,
            u32* __restrict__ cvals, u16* __restrict__ cidx) {
    const int tid = threadIdx.x;
    const int lane = tid & 63, w = tid >> 6;
    const int lo = lane & 31, hi = lane >> 5;
    const int gid = blockIdx.x;          // 0..3199
    const int panel = gid & 15;          // (b<<3)|split -> XCD affinity
    const int b = panel >> 3, split = panel & 7;
    const int nt = (gid >> 4) * 2 + w;   // compacted n-subtile
    const int NXb = hdr[8 + b];
    if (nt * 32 >= NXb) return;          // pad-col wave: exit (no barriers used)
    const int TPSr = hdr[6 + b] >> 8;    // tiles per split (MYpad/256)
    const int tbase = split * TPSr;

    const f16x8* fxq8 = (const f16x8*)fxq;
    const f16x8* fyb8 = (const f16x8*)fynq + ((size_t)(b * TMAX + tbase) * KS) * 64 + lane;

    u32 VMASK;
    asm("v_mov_b32 %0, 0xFFFFFC00" : "=v"(VMASK));

    f16x8 bfr[KS];
    #pragma unroll
    for (int ks = 0; ks < KS; ++ks)
        bfr[ks] = fxq8[((size_t)((b * TMAX + nt) * KS + ks)) * 64 + lane];

    f32x16 zvec = {};
    float b1 = 0.f, b2 = 0.f, b3 = 0.f, b4 = 0.f;

    f16x8 aA[KS], aB[KS];
    LDA(aA, 0);
    int t = 0;
    #pragma unroll 1
    for (; t + 1 < TPSr; t += 2) {
        LDA(aB, t + 1);
        CELL(aA, t);
        if (t + 2 < TPSr) LDA(aA, t + 2);
        CELL(aB, t + 1);
    }
    if (t < TPSr) CELL(aA, t);           // tail (TPSr odd)

    // candidates at COMPACTED row index: [b][n][split][hi][4]
    int n = nt * 32 + lo;
    size_t base = (((size_t)(b * N_ + n) * SPLIT + split) * 2 + hi) * LCAP;
    u32 pb0 = __float_as_uint(b1), pb1 = __float_as_uint(b2);
    u32 pb2 = __float_as_uint(b3), pb3 = __float_as_uint(b4);
    u32x4 pv = {pb0, pb1, pb2, pb3};
    u64 pidx = 0;
    u32 pbs[4] = {pb0, pb1, pb2, pb3};
    #pragma unroll
    for (int k = 0; k < 4; ++k) {
        int idx10 = (int)(pbs[k] & 1023u);
        int tl = idx10 >> 4, r = idx10 & 15;
        u32 mc = (u32)((tbase + tl) * 32 + (r & 3) + ((r >> 2) << 3) + (hi << 2));
        pidx |= (u64)(mc & 0xFFFFu) << (16 * k);
    }
    __builtin_nontemporal_store(pv, (u32x4*)&cvals[base]);
    __builtin_nontemporal_store(pidx, (u64*)&cidx[base]);
}

// ---------------------------------------------------------------------------
// Kernel 3: selective exact rescore over COMPACTED rows. Maps compacted ->
// original indices, recomputes the bit-identical round-1 fp32 dot for the
// t3-band, selects exact top-3 (tie: lower ORIGINAL index). Pad/junk
// candidates (score ~0, cmap->0) can never enter the band or win.
// ---------------------------------------------------------------------------
__global__ __launch_bounds__(256)
void rescore(const u32* __restrict__ cvals, const u16* __restrict__ cidx,
             const float* __restrict__ fxT, const float* __restrict__ fynT,
             const float* __restrict__ nyeps, const float* __restrict__ minf,
             const int* __restrict__ cmapX, const int* __restrict__ cmapY,
             const int* __restrict__ hdr, float* __restrict__ out) {
    int gwf = blockIdx.x * 4 + (threadIdx.x >> 6);
    int lane = threadIdx.x & 63;
    int b = gwf / N_, slot = gwf - b * N_;
    if (slot >= hdr[4 + b]) return;      // beyond compacted count
    int orig_n = cmapX[b * CMAPN + slot];

    float vn = __uint_as_float(cvals[(size_t)(b * N_ + slot) * CPR + lane]);
    int cm = cidx[(size_t)(b * N_ + slot) * CPR + lane];

    float cur = vn;
    float t3 = NEGINF;
    #pragma unroll
    for (int r = 0; r < 3; ++r) {
        float c = cur;
        #pragma unroll
        for (int off = 32; off >= 1; off >>= 1) c = fmaxf(c, __shfl_xor(c, off));
        t3 = c;
        cur = (cur == c) ? NEGINF : cur;
    }
    bool redo = (vn >= t3 - 0.125f);

    float rnk = NEGINF, wgt = 0.f;
    int midx = 0x7fffffff;
    if (redo) {
        int om = cmapY[b * CMAPN + cm];
        const float4* xq4 = (const float4*)(fxT + ((size_t)b * N_ + orig_n) * C_);
        const float4* fr4 = (const float4*)(fynT + ((size_t)b * N_ + om) * C_);
        float a = 0.f;
        #pragma unroll
        for (int c4 = 0; c4 < 16; ++c4) {
            float4 xf = xq4[c4];
            float4 f  = fr4[c4];
            a = fmaf(xf.x, f.x, a);
            a = fmaf(xf.y, f.y, a);
            a = fmaf(xf.z, f.z, a);
            a = fmaf(xf.w, f.w, a);
        }
        rnk = a + minf[(size_t)b * N_ + om];
        wgt = a * nyeps[(size_t)b * N_ + om];
        midx = om;
    }

    int wi[3]; float ww[3];
    #pragma unroll
    for (int r = 0; r < 3; ++r) {
        float cv = rnk; int ci = midx; float cw = wgt;
        #pragma unroll
        for (int off = 32; off >= 1; off >>= 1) {
            float ov = __shfl_xor(cv, off);
            int   oi = __shfl_xor(ci, off);
            float ow = __shfl_xor(cw, off);
            bool take = (ov > cv) || (ov == cv && oi < ci);
            cv = take ? ov : cv; ci = take ? oi : ci; cw = take ? ow : cw;
        }
        wi[r] = ci; ww[r] = cw;
        if (midx == ci) rnk = NEGINF;    // remove winner (and duplicates)
    }

    if (lane == 0) {
        float w0 = ww[0], w1 = ww[1], w2 = ww[2];
        float h0 = (float)(wi[0] / W_), h1 = (float)(wi[1] / W_), h2 = (float)(wi[2] / W_);
        float q0 = (float)(wi[0] % W_), q1 = (float)(wi[1] % W_), q2 = (float)(wi[2] % W_);
        float den = w0 + w1 + w2;
        float ph = (h0 * w0 + h1 * w1 + h2 * w2) / den;
        float pw = (q0 * w0 + q1 * w1 + q2 * w2) / den;
        out[2 * ((size_t)b * N_ + orig_n)]     = ph;   // row is valid by construction
        out[2 * ((size_t)b * N_ + orig_n) + 1] = pw;
    }
}

// ---------------------------------------------------------------------------
// Kernel 4: slic gather.
// ---------------------------------------------------------------------------
__global__ void slic_gather(const float* __restrict__ spg,
                            const float* __restrict__ pred,
                            float* __restrict__ outg) {
    int t = blockIdx.x * blockDim.x + threadIdx.x;
    if (t >= B_ * S_ * G_) return;
    int b = t / (S_ * G_);
    float vh = spg[2 * t], vw = spg[2 * t + 1];
    int ph = (int)rintf(vh * (float)H_);
    int pw = (int)rintf(vw * (float)H_);
    ph = ph < 0 ? 0 : (ph > H_ - 1 ? H_ - 1 : ph);
    pw = pw < 0 ? 0 : (pw > H_ - 1 ? H_ - 1 : pw);
    int lin = ph * W_ + pw;
    outg[2 * t]     = pred[((size_t)b * N_ + lin) * 2]     / (float)H_;
    outg[2 * t + 1] = pred[((size_t)b * N_ + lin) * 2 + 1] / (float)H_;
}

extern "C" void kernel_launch(void* const* d_in, const int* in_sizes, int n_in,
                              void* d_out, int out_size, void* d_ws, size_t ws_size,
                              hipStream_t stream) {
    const float* img1 = (const float*)d_in[0];
    const float* img2 = (const float*)d_in[1];
    const void*  mask1 = d_in[2];
    const void*  mask2 = d_in[3];
    const float* spg = (const float*)d_in[4];
    float* out = (float*)d_out;

    char* ws = (char*)d_ws;
    size_t off = 0;
    int*   hdr   = (int*)(ws + off);            off += 256;
    float* fynT  = (float*)(ws + off);          off += (size_t)B_ * N_ * C_ * 4;        // 6.42 MB
    float* fxT   = (float*)(ws + off);          off += (size_t)B_ * N_ * C_ * 4;        // 6.42 MB
    f16*   fxq   = (f16*)(ws + off);            off += (size_t)B_ * TMAX * KS * 64 * 16; // 4.1 MB
    f16*   fynq  = (f16*)(ws + off);            off += (size_t)B_ * TMAX * KS * 64 * 16; // 4.1 MB
    float* nyeps = (float*)(ws + off);          off += (size_t)B_ * N_ * 4;
    float* minf  = (float*)(ws + off);          off += (size_t)B_ * N_ * 4;
    int*   cmapY = (int*)(ws + off);            off += (size_t)B_ * CMAPN * 4;
    int*   cmapX = (int*)(ws + off);            off += (size_t)B_ * CMAPN * 4;
    u32*   cvals = (u32*)(ws + off);            off += (size_t)B_ * N_ * CPR * 4;       // 6.42 MB
    u16*   cidx  = (u16*)(ws + off);            off += (size_t)B_ * N_ * CPR * 2;       // 3.21 MB

    detect_fmt<<<1, 1024, 0, stream>>>((const u32*)mask1, (const u32*)mask2,
                                       (B_ * N_) / 4, hdr);
    dim3 gp((B_ * N_) / 256, 2);
    prep<<<gp, 256, 0, stream>>>(img1, img2,
                                 (const unsigned char*)mask1,
                                 (const unsigned char*)mask2, hdr,
                                 fxq, fxT, fynT, fynq, nyeps, minf,
                                 cmapX, cmapY, out);
    padfill<<<1, 512, 0, stream>>>(hdr, (uint4*)fynq, (uint4*)fxq, cmapY, cmapX);

    stage1<<<3200, 128, 0, stream>>>(fxq, fynq, hdr, cvals, cidx);

    rescore<<<(B_ * N_) / 4, 256, 0, stream>>>(
        cvals, cidx, fxT, fynT, nyeps, minf, cmapX, cmapY, hdr, out);

    slic_gather<<<(B_ * S_ * G_ + 255) / 256, 256, 0, stream>>>(
        spg, out, out + (size_t)B_ * N_ * 2);
}

// Round 18
// 92.802 us; speedup vs baseline: 3.9218x; 3.9218x over previous
//
#include <hip/hip_runtime.h>
#include <math.h>

typedef _Float16 f16;
typedef f16 f16x8 __attribute__((ext_vector_type(8)));
typedef float f32x16 __attribute__((ext_vector_type(16)));
typedef unsigned short u16;
typedef unsigned int u32;
typedef unsigned long long u64;
typedef u32 u32x4 __attribute__((ext_vector_type(4)));

#define B_ 2
#define C_ 64
#define KS 5              // 64 feats + bias(k=64) + zero pad
#define H_ 112
#define W_ 112
#define N_ 12544
#define S_ 50
#define G_ 120
#define SPLIT 8
#define LCAP 4
#define CPR (SPLIT*2*LCAP)  // 64 candidates per compacted row
#define TMAX 400            // allocated tiles per batch
#define CMAPN 12800         // compacted-slot map capacity per batch
#define CH 13               // elements per scan thread (13*1024 >= 12544)

#define NEGINF (-__builtin_inff())
#define FMED3 __builtin_amdgcn_fmed3f

union U16B { uint4 u; f16x8 h; f16 e[8]; };

// hdr layout: [0]=flag1 [1]=flag2 [2..3]=cntY[b] [4..5]=cntX[b]
//             [6..7]=MYpad[b] (mult 256)  [8..9]=NXpad[b] (mult 64)

// ---------------------------------------------------------------------------
// Kernel 0: mask format detect (byte vs int32).
// ---------------------------------------------------------------------------
__global__ void detect_fmt(const u32* __restrict__ m1, const u32* __restrict__ m2,
                           int nw, int* __restrict__ hdr) {
    __shared__ u32 s[2];
    if (threadIdx.x == 0) { s[0] = 0; s[1] = 0; }
    __syncthreads();
    u32 a = 0, bb = 0;
    for (int i = threadIdx.x; i < nw; i += blockDim.x) {
        a  |= m1[i] & 0xFFFFFF00u;
        bb |= m2[i] & 0xFFFFFF00u;
    }
    if (a)  atomicOr(&s[0], 1u);
    if (bb) atomicOr(&s[1], 1u);
    __syncthreads();
    if (threadIdx.x == 0) { hdr[0] = s[0] ? 1 : 0; hdr[1] = s[1] ? 1 : 0; }
}

// ---------------------------------------------------------------------------
// Kernel 0b: deterministic compaction scan — NO atomics (R17's prep died on
// single-address atomicAdd serialization: 296 us, VALUBusy 0.26%).
// One block per (side, batch): block-wide exclusive prefix over 12544 valid
// flags (13 elems/thread bitmask + Hillis-Steele over LDS). Writes
// slotmap[pixel] (slot or -1), cmap[slot]=pixel (sorted), count -> hdr.
// ---------------------------------------------------------------------------
__global__ __launch_bounds__(1024)
void scan_compact(const unsigned char* __restrict__ m1,
                  const unsigned char* __restrict__ m2,
                  int* __restrict__ hdr,
                  int* __restrict__ slotX, int* __restrict__ slotY,
                  int* __restrict__ cmapX, int* __restrict__ cmapY) {
    const int side = blockIdx.x >> 1;    // 0 = X(mask1), 1 = Y(mask2)
    const int b = blockIdx.x & 1;
    const unsigned char* mk = side ? m2 : m1;
    const int flag = hdr[side];
    int* slotmap = side ? slotY : slotX;
    int* cmap    = side ? cmapY : cmapX;
    const int cntidx = side ? (2 + b) : (4 + b);

    __shared__ int ssum[1024];
    const int tid = threadIdx.x;
    const int m0 = tid * CH;

    u32 vbits = 0; int cnt = 0;
    #pragma unroll
    for (int i = 0; i < CH; ++i) {
        int m = m0 + i;
        int v = 0;
        if (m < N_) {
            int t = b * N_ + m;
            v = flag ? (mk[t] != 0) : (((const int*)mk)[t] != 0);
        }
        vbits |= (u32)v << i;
        cnt += v;
    }
    ssum[tid] = cnt;
    __syncthreads();
    #pragma unroll
    for (int d = 1; d < 1024; d <<= 1) {
        int v = (tid >= d) ? ssum[tid - d] : 0;
        __syncthreads();
        ssum[tid] += v;
        __syncthreads();
    }
    int slot = ssum[tid] - cnt;          // exclusive prefix
    #pragma unroll
    for (int i = 0; i < CH; ++i) {
        int m = m0 + i;
        if (m < N_) {
            int t = b * N_ + m;
            if ((vbits >> i) & 1) {
                slotmap[t] = slot;
                cmap[b * CMAPN + slot] = m;
                slot++;
            } else slotmap[t] = -1;
        }
    }
    if (tid == 1023) hdr[cntidx] = ssum[1023];
}

// ---------------------------------------------------------------------------
// Kernel 1 (fused, compaction via precomputed slots — no atomics):
// y==0 (src/x): fxT always; invalid -> out=-1 prefill; valid -> fxq frags at
//   slotX[t] (k<64: v; k==64: 1.0; else 0).
// y==1 (dst/y): fynT/nyeps/minf always (round-1 arithmetic); valid -> fynq
//   frags at slotY[t] (k<64: v/ny; k==64: +128 bias; else 0).
// ---------------------------------------------------------------------------
__global__ void prep(const float* __restrict__ fx, const float* __restrict__ fy,
                     const unsigned char* __restrict__ mask2b,
                     const int* __restrict__ hdr,
                     const int* __restrict__ slotX, const int* __restrict__ slotY,
                     f16* __restrict__ fxq, float* __restrict__ fxT,
                     float* __restrict__ fynT, f16* __restrict__ fynq,
                     float* __restrict__ nyeps, float* __restrict__ minf,
                     float* __restrict__ out) {
    int t = blockIdx.x * blockDim.x + threadIdx.x;   // t = b*N + pixel
    if (t >= B_ * N_) return;
    int b = t / N_;

    if (blockIdx.y == 0) {
        const float* src = fx + (size_t)b * C_ * N_ + (t - b * N_);
        float v[64];
        #pragma unroll
        for (int c = 0; c < C_; ++c) v[c] = src[(size_t)c * N_];

        float4* xT = (float4*)(fxT + (size_t)t * C_);
        #pragma unroll
        for (int c4 = 0; c4 < 16; ++c4)
            xT[c4] = make_float4(v[c4*4], v[c4*4+1], v[c4*4+2], v[c4*4+3]);

        int slot = slotX[t];
        if (slot < 0) {
            out[2 * (size_t)t] = -1.0f;
            out[2 * (size_t)t + 1] = -1.0f;
            return;
        }
        int tile = slot >> 5, r = slot & 31;
        uint4* q4 = (uint4*)fxq;
        size_t cb = (size_t)(b * TMAX + tile) * (KS * 64);
        #pragma unroll
        for (int ks = 0; ks < KS; ++ks) {
            #pragma unroll
            for (int hi = 0; hi < 2; ++hi) {
                U16B tmp;
                #pragma unroll
                for (int i = 0; i < 8; ++i) {
                    int k = 16 * ks + 8 * hi + i;
                    float val = (k < 64) ? v[k] : ((k == 64) ? 1.0f : 0.0f);
                    tmp.e[i] = (f16)val;
                }
                q4[cb + (size_t)ks * 64 + hi * 32 + r] = tmp.u;
            }
        }
    } else {
        const float* src = fy + (size_t)b * C_ * N_ + (t - b * N_);
        float v[64];
        float ss = 0.f;
        #pragma unroll
        for (int c = 0; c < C_; ++c) { v[c] = src[(size_t)c * N_]; ss = fmaf(v[c], v[c], ss); }
        float ny = sqrtf(ss) + 1e-12f;
        nyeps[t] = ny;
        int slot = slotY[t];
        minf[t] = (slot >= 0) ? 0.0f : NEGINF;

        float* dT = fynT + (size_t)t * C_;
        #pragma unroll
        for (int c = 0; c < C_; ++c) dT[c] = v[c] / ny;   // round-1 arithmetic

        if (slot < 0) return;
        int tile = slot >> 5, r = slot & 31;
        uint4* q4 = (uint4*)fynq;
        size_t cb = (size_t)(b * TMAX + tile) * (KS * 64);
        #pragma unroll
        for (int ks = 0; ks < KS; ++ks) {
            #pragma unroll
            for (int hi = 0; hi < 2; ++hi) {
                U16B tmp;
                #pragma unroll
                for (int i = 0; i < 8; ++i) {
                    int k = 16 * ks + 8 * hi + i;
                    float val = (k < 64) ? (v[k] / ny) : ((k == 64) ? 128.0f : 0.0f);
                    tmp.e[i] = (f16)val;
                }
                q4[cb + (size_t)ks * 64 + hi * 32 + r] = tmp.u;
            }
        }
    }
}

// ---------------------------------------------------------------------------
// Kernel 1b: padded sizes; zero-fill pad rows/cols (score ~0 vs real ~128 ->
// pads never become candidates); pad cmap entries -> 0.
// ---------------------------------------------------------------------------
__global__ void padfill(int* __restrict__ hdr, uint4* __restrict__ fynq4,
                        uint4* __restrict__ fxq4, int* __restrict__ cmapY,
                        int* __restrict__ cmapX) {
    int tid = threadIdx.x;
    __shared__ int sMY[2], sNX[2], sCY[2], sCX[2];
    if (tid == 0) {
        for (int b = 0; b < B_; ++b) {
            int cy = hdr[2 + b], cx = hdr[4 + b];
            int my = (cy + 255) & ~255;
            int nx = (cx + 63) & ~63;
            hdr[6 + b] = my; hdr[8 + b] = nx;
            sMY[b] = my; sNX[b] = nx; sCY[b] = cy; sCX[b] = cx;
        }
    }
    __syncthreads();
    uint4 z = make_uint4(0, 0, 0, 0);
    for (int b = 0; b < B_; ++b) {
        for (int p = sCY[b] + tid; p < sMY[b]; p += blockDim.x) {
            cmapY[b * CMAPN + p] = 0;
            int tile = p >> 5, r = p & 31;
            size_t cb = (size_t)(b * TMAX + tile) * (KS * 64);
            #pragma unroll
            for (int ks = 0; ks < KS; ++ks) {
                fynq4[cb + (size_t)ks * 64 + r] = z;
                fynq4[cb + (size_t)ks * 64 + 32 + r] = z;
            }
        }
        for (int p = sCX[b] + tid; p < sNX[b]; p += blockDim.x) {
            cmapX[b * CMAPN + p] = 0;
            int tile = p >> 5, r = p & 31;
            size_t cb = (size_t)(b * TMAX + tile) * (KS * 64);
            #pragma unroll
            for (int ks = 0; ks < KS; ++ks) {
                fxq4[cb + (size_t)ks * 64 + r] = z;
                fxq4[cb + (size_t)ks * 64 + 32 + r] = z;
            }
        }
    }
}

// ---------------------------------------------------------------------------
// Kernel 2: MFMA candidate pass on COMPACTED matrices (~1/4 the cells).
// ---------------------------------------------------------------------------
#define LDA(dst, t) { _Pragma("unroll") \
    for (int ks = 0; ks < KS; ++ks) \
        dst[ks] = fyb8[((size_t)(t) * KS + ks) * 64]; }

#define MFMAC(acc, a) { \
    acc = __builtin_amdgcn_mfma_f32_32x32x16_f16(a[0], bfr[0], zvec, 0, 0, 0); \
    acc = __builtin_amdgcn_mfma_f32_32x32x16_f16(a[1], bfr[1], acc, 0, 0, 0); \
    acc = __builtin_amdgcn_mfma_f32_32x32x16_f16(a[2], bfr[2], acc, 0, 0, 0); \
    acc = __builtin_amdgcn_mfma_f32_32x32x16_f16(a[3], bfr[3], acc, 0, 0, 0); \
    acc = __builtin_amdgcn_mfma_f32_32x32x16_f16(a[4], bfr[4], acc, 0, 0, 0); }

#define EXTRACT(acc, bse) { \
    _Pragma("unroll") \
    for (int r = 0; r < 16; ++r) { \
        u32 pb_ = (__float_as_uint(acc[r]) & VMASK) | ((bse) + (u32)r); \
        float p_ = __uint_as_float(pb_); \
        b4 = FMED3(p_, b3, b4); \
        b3 = FMED3(p_, b2, b3); \
        b2 = FMED3(p_, b1, b2); \
        b1 = fmaxf(p_, b1); } }

#define CELL(a, t) { f32x16 acc_; MFMAC(acc_, a); EXTRACT(acc_, (u32)((t) * 16)); }

__global__ __launch_bounds__(128, 4)
void stage1(const f16* __restrict__ fxq, const f16* __restrict__ fynq,
            const int* __restrict__ hdr,
            u32* __restrict__ cvals, u16* __restrict__ cidx) {
    const int tid = threadIdx.x;
    const int lane = tid & 63, w = tid >> 6;
    const int lo = lane & 31, hi = lane >> 5;
    const int gid = blockIdx.x;          // 0..3199
    const int panel = gid & 15;          // (b<<3)|split -> XCD affinity
    const int b = panel >> 3, split = panel & 7;
    const int nt = (gid >> 4) * 2 + w;   // compacted n-subtile
    const int NXb = hdr[8 + b];
    if (nt * 32 >= NXb) return;          // pad-col wave: exit (no barriers)
    const int TPSr = hdr[6 + b] >> 8;    // tiles per split (MYpad/256)
    const int tbase = split * TPSr;

    const f16x8* fxq8 = (const f16x8*)fxq;
    const f16x8* fyb8 = (const f16x8*)fynq + ((size_t)(b * TMAX + tbase) * KS) * 64 + lane;

    u32 VMASK;
    asm("v_mov_b32 %0, 0xFFFFFC00" : "=v"(VMASK));

    f16x8 bfr[KS];
    #pragma unroll
    for (int ks = 0; ks < KS; ++ks)
        bfr[ks] = fxq8[((size_t)((b * TMAX + nt) * KS + ks)) * 64 + lane];

    f32x16 zvec = {};
    float b1 = 0.f, b2 = 0.f, b3 = 0.f, b4 = 0.f;

    f16x8 aA[KS], aB[KS];
    LDA(aA, 0);
    int t = 0;
    #pragma unroll 1
    for (; t + 1 < TPSr; t += 2) {
        LDA(aB, t + 1);
        CELL(aA, t);
        if (t + 2 < TPSr) LDA(aA, t + 2);
        CELL(aB, t + 1);
    }
    if (t < TPSr) CELL(aA, t);           // tail (TPSr odd)

    // candidates at COMPACTED row index: [b][n][split][hi][4]
    int n = nt * 32 + lo;
    size_t base = (((size_t)(b * N_ + n) * SPLIT + split) * 2 + hi) * LCAP;
    u32 pb0 = __float_as_uint(b1), pb1 = __float_as_uint(b2);
    u32 pb2 = __float_as_uint(b3), pb3 = __float_as_uint(b4);
    u32x4 pv = {pb0, pb1, pb2, pb3};
    u64 pidx = 0;
    u32 pbs[4] = {pb0, pb1, pb2, pb3};
    #pragma unroll
    for (int k = 0; k < 4; ++k) {
        int idx10 = (int)(pbs[k] & 1023u);
        int tl = idx10 >> 4, r = idx10 & 15;
        u32 mc = (u32)((tbase + tl) * 32 + (r & 3) + ((r >> 2) << 3) + (hi << 2));
        pidx |= (u64)(mc & 0xFFFFu) << (16 * k);
    }
    __builtin_nontemporal_store(pv, (u32x4*)&cvals[base]);
    __builtin_nontemporal_store(pidx, (u64*)&cidx[base]);
}

// ---------------------------------------------------------------------------
// Kernel 3: selective exact rescore over COMPACTED rows (maps back to
// original indices; bit-identical round-1 fp32 dot; tie: lower orig index).
// ---------------------------------------------------------------------------
__global__ __launch_bounds__(256)
void rescore(const u32* __restrict__ cvals, const u16* __restrict__ cidx,
             const float* __restrict__ fxT, const float* __restrict__ fynT,
             const float* __restrict__ nyeps, const float* __restrict__ minf,
             const int* __restrict__ cmapX, const int* __restrict__ cmapY,
             const int* __restrict__ hdr, float* __restrict__ out) {
    int gwf = blockIdx.x * 4 + (threadIdx.x >> 6);
    int lane = threadIdx.x & 63;
    int b = gwf / N_, slot = gwf - b * N_;
    if (slot >= hdr[4 + b]) return;
    int orig_n = cmapX[b * CMAPN + slot];

    float vn = __uint_as_float(cvals[(size_t)(b * N_ + slot) * CPR + lane]);
    int cm = cidx[(size_t)(b * N_ + slot) * CPR + lane];

    float cur = vn;
    float t3 = NEGINF;
    #pragma unroll
    for (int r = 0; r < 3; ++r) {
        float c = cur;
        #pragma unroll
        for (int off = 32; off >= 1; off >>= 1) c = fmaxf(c, __shfl_xor(c, off));
        t3 = c;
        cur = (cur == c) ? NEGINF : cur;
    }
    bool redo = (vn >= t3 - 0.125f);

    float rnk = NEGINF, wgt = 0.f;
    int midx = 0x7fffffff;
    if (redo) {
        int om = cmapY[b * CMAPN + cm];
        const float4* xq4 = (const float4*)(fxT + ((size_t)b * N_ + orig_n) * C_);
        const float4* fr4 = (const float4*)(fynT + ((size_t)b * N_ + om) * C_);
        float a = 0.f;
        #pragma unroll
        for (int c4 = 0; c4 < 16; ++c4) {
            float4 xf = xq4[c4];
            float4 f  = fr4[c4];
            a = fmaf(xf.x, f.x, a);
            a = fmaf(xf.y, f.y, a);
            a = fmaf(xf.z, f.z, a);
            a = fmaf(xf.w, f.w, a);
        }
        rnk = a + minf[(size_t)b * N_ + om];
        wgt = a * nyeps[(size_t)b * N_ + om];
        midx = om;
    }

    int wi[3]; float ww[3];
    #pragma unroll
    for (int r = 0; r < 3; ++r) {
        float cv = rnk; int ci = midx; float cw = wgt;
        #pragma unroll
        for (int off = 32; off >= 1; off >>= 1) {
            float ov = __shfl_xor(cv, off);
            int   oi = __shfl_xor(ci, off);
            float ow = __shfl_xor(cw, off);
            bool take = (ov > cv) || (ov == cv && oi < ci);
            cv = take ? ov : cv; ci = take ? oi : ci; cw = take ? ow : cw;
        }
        wi[r] = ci; ww[r] = cw;
        if (midx == ci) rnk = NEGINF;
    }

    if (lane == 0) {
        float w0 = ww[0], w1 = ww[1], w2 = ww[2];
        float h0 = (float)(wi[0] / W_), h1 = (float)(wi[1] / W_), h2 = (float)(wi[2] / W_);
        float q0 = (float)(wi[0] % W_), q1 = (float)(wi[1] % W_), q2 = (float)(wi[2] % W_);
        float den = w0 + w1 + w2;
        float ph = (h0 * w0 + h1 * w1 + h2 * w2) / den;
        float pw = (q0 * w0 + q1 * w1 + q2 * w2) / den;
        out[2 * ((size_t)b * N_ + orig_n)]     = ph;
        out[2 * ((size_t)b * N_ + orig_n) + 1] = pw;
    }
}

// ---------------------------------------------------------------------------
// Kernel 4: slic gather.
// ---------------------------------------------------------------------------
__global__ void slic_gather(const float* __restrict__ spg,
                            const float* __restrict__ pred,
                            float* __restrict__ outg) {
    int t = blockIdx.x * blockDim.x + threadIdx.x;
    if (t >= B_ * S_ * G_) return;
    int b = t / (S_ * G_);
    float vh = spg[2 * t], vw = spg[2 * t + 1];
    int ph = (int)rintf(vh * (float)H_);
    int pw = (int)rintf(vw * (float)H_);
    ph = ph < 0 ? 0 : (ph > H_ - 1 ? H_ - 1 : ph);
    pw = pw < 0 ? 0 : (pw > H_ - 1 ? H_ - 1 : pw);
    int lin = ph * W_ + pw;
    outg[2 * t]     = pred[((size_t)b * N_ + lin) * 2]     / (float)H_;
    outg[2 * t + 1] = pred[((size_t)b * N_ + lin) * 2 + 1] / (float)H_;
}

extern "C" void kernel_launch(void* const* d_in, const int* in_sizes, int n_in,
                              void* d_out, int out_size, void* d_ws, size_t ws_size,
                              hipStream_t stream) {
    const float* img1 = (const float*)d_in[0];
    const float* img2 = (const float*)d_in[1];
    const void*  mask1 = d_in[2];
    const void*  mask2 = d_in[3];
    const float* spg = (const float*)d_in[4];
    float* out = (float*)d_out;

    char* ws = (char*)d_ws;
    size_t off = 0;
    int*   hdr   = (int*)(ws + off);            off += 256;
    float* fynT  = (float*)(ws + off);          off += (size_t)B_ * N_ * C_ * 4;         // 6.42 MB
    float* fxT   = (float*)(ws + off);          off += (size_t)B_ * N_ * C_ * 4;         // 6.42 MB
    f16*   fxq   = (f16*)(ws + off);            off += (size_t)B_ * TMAX * KS * 64 * 16; // 4.1 MB
    f16*   fynq  = (f16*)(ws + off);            off += (size_t)B_ * TMAX * KS * 64 * 16; // 4.1 MB
    float* nyeps = (float*)(ws + off);          off += (size_t)B_ * N_ * 4;
    float* minf  = (float*)(ws + off);          off += (size_t)B_ * N_ * 4;
    int*   cmapY = (int*)(ws + off);            off += (size_t)B_ * CMAPN * 4;
    int*   cmapX = (int*)(ws + off);            off += (size_t)B_ * CMAPN * 4;
    int*   slotX = (int*)(ws + off);            off += (size_t)B_ * N_ * 4;
    int*   slotY = (int*)(ws + off);            off += (size_t)B_ * N_ * 4;
    u32*   cvals = (u32*)(ws + off);            off += (size_t)B_ * N_ * CPR * 4;        // 6.42 MB
    u16*   cidx  = (u16*)(ws + off);            off += (size_t)B_ * N_ * CPR * 2;        // 3.21 MB

    detect_fmt<<<1, 1024, 0, stream>>>((const u32*)mask1, (const u32*)mask2,
                                       (B_ * N_) / 4, hdr);
    scan_compact<<<4, 1024, 0, stream>>>((const unsigned char*)mask1,
                                         (const unsigned char*)mask2, hdr,
                                         slotX, slotY, cmapX, cmapY);
    dim3 gp((B_ * N_) / 256, 2);
    prep<<<gp, 256, 0, stream>>>(img1, img2, (const unsigned char*)mask2, hdr,
                                 slotX, slotY, fxq, fxT, fynT, fynq,
                                 nyeps, minf, out);
    padfill<<<1, 512, 0, stream>>>(hdr, (uint4*)fynq, (uint4*)fxq, cmapY, cmapX);

    stage1<<<3200, 128, 0, stream>>>(fxq, fynq, hdr, cvals, cidx);

    rescore<<<(B_ * N_) / 4, 256, 0, stream>>>(
        cvals, cidx, fxT, fynT, nyeps, minf, cmapX, cmapY, hdr, out);

    slic_gather<<<(B_ * S_ * G_ + 255) / 256, 256, 0, stream>>>(
        spg, out, out + (size_t)B_ * N_ * 2);
}

// Round 19
// 88.643 us; speedup vs baseline: 4.1058x; 1.0469x over previous
//
#include <hip/hip_runtime.h>
#include <math.h>

typedef _Float16 f16;
typedef f16 f16x8 __attribute__((ext_vector_type(8)));
typedef float f32x16 __attribute__((ext_vector_type(16)));
typedef unsigned short u16;
typedef unsigned int u32;
typedef unsigned long long u64;
typedef u32 u32x4 __attribute__((ext_vector_type(4)));

#define B_ 2
#define C_ 64
#define KS 5              // 64 feats + bias(k=64) + zero pad
#define H_ 112
#define W_ 112
#define N_ 12544
#define S_ 50
#define G_ 120
#define SPLIT 8
#define LCAP 4
#define CPR (SPLIT*2*LCAP)  // 64 candidates per compacted row
#define TMAX 400            // allocated tiles per batch
#define CMAPN 12800         // compacted-slot map capacity per batch
#define CH 13               // elements per scan thread (13*1024 >= 12544)

#define NEGINF (-__builtin_inff())
#define FMED3 __builtin_amdgcn_fmed3f

union U16B { uint4 u; f16x8 h; f16 e[8]; };

// hdr layout: [2..3]=cntY[b]  [4..5]=cntX[b]

// ---------------------------------------------------------------------------
// Kernel Z: grid-stride zero of fxq/fynq/cmaps. Replaces padfill: pad rows
// score ~0 vs real ~128 (bias channel) -> never become candidates; pad cmap
// entries point at pixel 0 (harmless, can't win rescore).
// ---------------------------------------------------------------------------
__global__ void zerofill(uint4* __restrict__ fxq4, uint4* __restrict__ fynq4,
                         int* __restrict__ cmapX, int* __restrict__ cmapY) {
    int i = blockIdx.x * blockDim.x + threadIdx.x;
    int stride = gridDim.x * blockDim.x;
    uint4 z = make_uint4(0, 0, 0, 0);
    const int NQ = B_ * TMAX * KS * 64;          // uint4 count per buffer
    for (int k = i; k < NQ; k += stride) { fxq4[k] = z; fynq4[k] = z; }
    const int NC = B_ * CMAPN;
    for (int k = i; k < NC; k += stride) { cmapX[k] = 0; cmapY[k] = 0; }
}

// ---------------------------------------------------------------------------
// Kernel 0: compaction scan, atomic-free, with INLINE format detect.
// One block per (side, batch). Format: OR over the full side tensor's
// high bytes (int32 0/1 data has none; byte bools ~half set). Then a
// block-wide exclusive prefix over this batch's 12544 valid flags
// (13 elems/thread bitmask + Hillis-Steele). Writes slotmap (pixel->slot
// or -1), cmap (slot->pixel, sorted), count -> hdr.
// ---------------------------------------------------------------------------
__global__ __launch_bounds__(1024)
void scan_compact(const unsigned char* __restrict__ m1,
                  const unsigned char* __restrict__ m2,
                  int* __restrict__ hdr,
                  int* __restrict__ slotX, int* __restrict__ slotY,
                  int* __restrict__ cmapX, int* __restrict__ cmapY) {
    const int side = blockIdx.x >> 1;    // 0 = X(mask1), 1 = Y(mask2)
    const int b = blockIdx.x & 1;
    const unsigned char* mk = side ? m2 : m1;
    int* slotmap = side ? slotY : slotX;
    int* cmap    = side ? cmapY : cmapX;
    const int cntidx = side ? (2 + b) : (4 + b);
    const int tid = threadIdx.x;

    __shared__ int sflag;
    __shared__ int ssum[1024];
    if (tid == 0) sflag = 0;
    __syncthreads();
    const u32* mw = (const u32*)mk;
    u32 acc = 0;
    for (int i = tid; i < (B_ * N_) / 4; i += 1024) acc |= mw[i] & 0xFFFFFF00u;
    if (acc) atomicOr(&sflag, 1);
    __syncthreads();
    const int flag = sflag;              // 1 => byte bools

    const int m0 = tid * CH;
    u32 vbits = 0; int cnt = 0;
    #pragma unroll
    for (int i = 0; i < CH; ++i) {
        int m = m0 + i;
        int v = 0;
        if (m < N_) {
            int t = b * N_ + m;
            v = flag ? (mk[t] != 0) : (((const int*)mk)[t] != 0);
        }
        vbits |= (u32)v << i;
        cnt += v;
    }
    ssum[tid] = cnt;
    __syncthreads();
    #pragma unroll
    for (int d = 1; d < 1024; d <<= 1) {
        int v = (tid >= d) ? ssum[tid - d] : 0;
        __syncthreads();
        ssum[tid] += v;
        __syncthreads();
    }
    int slot = ssum[tid] - cnt;          // exclusive prefix
    #pragma unroll
    for (int i = 0; i < CH; ++i) {
        int m = m0 + i;
        if (m < N_) {
            int t = b * N_ + m;
            if ((vbits >> i) & 1) {
                slotmap[t] = slot;
                cmap[b * CMAPN + slot] = m;
                slot++;
            } else slotmap[t] = -1;
        }
    }
    if (tid == 1023) hdr[cntidx] = ssum[1023];
}

// ---------------------------------------------------------------------------
// Kernel 1 (fused prep, slot-driven, atomic-free):
// y==0 (src/x): fxT always; invalid -> out=-1 prefill; valid -> fxq frags at
//   slotX[t] (k<64: v; k==64: 1.0; else 0).
// y==1 (dst/y): fynT/nyeps/minf always (round-1 arithmetic, division done
//   ONCE and reused for the f16 frag); valid -> fynq frags at slotY[t]
//   (k<64: v/ny; k==64: +128 bias -> all stage1 scores positive; else 0).
// ---------------------------------------------------------------------------
__global__ void prep(const float* __restrict__ fx, const float* __restrict__ fy,
                     const int* __restrict__ slotX, const int* __restrict__ slotY,
                     f16* __restrict__ fxq, float* __restrict__ fxT,
                     float* __restrict__ fynT, f16* __restrict__ fynq,
                     float* __restrict__ nyeps, float* __restrict__ minf,
                     float* __restrict__ out) {
    int t = blockIdx.x * blockDim.x + threadIdx.x;   // t = b*N + pixel
    if (t >= B_ * N_) return;
    int b = t / N_;

    if (blockIdx.y == 0) {
        const float* src = fx + (size_t)b * C_ * N_ + (t - b * N_);
        float v[64];
        #pragma unroll
        for (int c = 0; c < C_; ++c) v[c] = src[(size_t)c * N_];

        float4* xT = (float4*)(fxT + (size_t)t * C_);
        #pragma unroll
        for (int c4 = 0; c4 < 16; ++c4)
            xT[c4] = make_float4(v[c4*4], v[c4*4+1], v[c4*4+2], v[c4*4+3]);

        int slot = slotX[t];
        if (slot < 0) {
            out[2 * (size_t)t] = -1.0f;
            out[2 * (size_t)t + 1] = -1.0f;
            return;
        }
        int tile = slot >> 5, r = slot & 31;
        uint4* q4 = (uint4*)fxq;
        size_t cb = (size_t)(b * TMAX + tile) * (KS * 64);
        #pragma unroll
        for (int ks = 0; ks < KS; ++ks) {
            #pragma unroll
            for (int hi = 0; hi < 2; ++hi) {
                U16B tmp;
                #pragma unroll
                for (int i = 0; i < 8; ++i) {
                    int k = 16 * ks + 8 * hi + i;
                    float val = (k < 64) ? v[k] : ((k == 64) ? 1.0f : 0.0f);
                    tmp.e[i] = (f16)val;
                }
                q4[cb + (size_t)ks * 64 + hi * 32 + r] = tmp.u;
            }
        }
    } else {
        const float* src = fy + (size_t)b * C_ * N_ + (t - b * N_);
        float v[64], dv[64];
        float ss = 0.f;
        #pragma unroll
        for (int c = 0; c < C_; ++c) { v[c] = src[(size_t)c * N_]; ss = fmaf(v[c], v[c], ss); }
        float ny = sqrtf(ss) + 1e-12f;
        nyeps[t] = ny;
        int slot = slotY[t];
        minf[t] = (slot >= 0) ? 0.0f : NEGINF;

        float* dT = fynT + (size_t)t * C_;
        #pragma unroll
        for (int c = 0; c < C_; ++c) { dv[c] = v[c] / ny; dT[c] = dv[c]; }  // round-1 arithmetic, once

        if (slot < 0) return;
        int tile = slot >> 5, r = slot & 31;
        uint4* q4 = (uint4*)fynq;
        size_t cb = (size_t)(b * TMAX + tile) * (KS * 64);
        #pragma unroll
        for (int ks = 0; ks < KS; ++ks) {
            #pragma unroll
            for (int hi = 0; hi < 2; ++hi) {
                U16B tmp;
                #pragma unroll
                for (int i = 0; i < 8; ++i) {
                    int k = 16 * ks + 8 * hi + i;
                    float val = (k < 64) ? dv[k] : ((k == 64) ? 128.0f : 0.0f);
                    tmp.e[i] = (f16)val;
                }
                q4[cb + (size_t)ks * 64 + hi * 32 + r] = tmp.u;
            }
        }
    }
}

// ---------------------------------------------------------------------------
// Kernel 2: MFMA candidate pass on COMPACTED matrices (~1/4 the cells).
// Padded bounds computed inline from raw counts (padfill kernel removed).
// ---------------------------------------------------------------------------
#define LDA(dst, t) { _Pragma("unroll") \
    for (int ks = 0; ks < KS; ++ks) \
        dst[ks] = fyb8[((size_t)(t) * KS + ks) * 64]; }

#define MFMAC(acc, a) { \
    acc = __builtin_amdgcn_mfma_f32_32x32x16_f16(a[0], bfr[0], zvec, 0, 0, 0); \
    acc = __builtin_amdgcn_mfma_f32_32x32x16_f16(a[1], bfr[1], acc, 0, 0, 0); \
    acc = __builtin_amdgcn_mfma_f32_32x32x16_f16(a[2], bfr[2], acc, 0, 0, 0); \
    acc = __builtin_amdgcn_mfma_f32_32x32x16_f16(a[3], bfr[3], acc, 0, 0, 0); \
    acc = __builtin_amdgcn_mfma_f32_32x32x16_f16(a[4], bfr[4], acc, 0, 0, 0); }

#define EXTRACT(acc, bse) { \
    _Pragma("unroll") \
    for (int r = 0; r < 16; ++r) { \
        u32 pb_ = (__float_as_uint(acc[r]) & VMASK) | ((bse) + (u32)r); \
        float p_ = __uint_as_float(pb_); \
        b4 = FMED3(p_, b3, b4); \
        b3 = FMED3(p_, b2, b3); \
        b2 = FMED3(p_, b1, b2); \
        b1 = fmaxf(p_, b1); } }

#define CELL(a, t) { f32x16 acc_; MFMAC(acc_, a); EXTRACT(acc_, (u32)((t) * 16)); }

__global__ __launch_bounds__(128, 4)
void stage1(const f16* __restrict__ fxq, const f16* __restrict__ fynq,
            const int* __restrict__ hdr,
            u32* __restrict__ cvals, u16* __restrict__ cidx) {
    const int tid = threadIdx.x;
    const int lane = tid & 63, w = tid >> 6;
    const int lo = lane & 31, hi = lane >> 5;
    const int gid = blockIdx.x;          // 0..3199
    const int panel = gid & 15;          // (b<<3)|split -> XCD affinity
    const int b = panel >> 3, split = panel & 7;
    const int nt = (gid >> 4) * 2 + w;   // compacted n-subtile
    const int NXb = (hdr[4 + b] + 63) & ~63;
    if (nt * 32 >= NXb) return;          // pad-col wave: exit (no barriers)
    const int TPSr = ((hdr[2 + b] + 255) & ~255) >> 8;   // tiles per split
    const int tbase = split * TPSr;

    const f16x8* fxq8 = (const f16x8*)fxq;
    const f16x8* fyb8 = (const f16x8*)fynq + ((size_t)(b * TMAX + tbase) * KS) * 64 + lane;

    u32 VMASK;
    asm("v_mov_b32 %0, 0xFFFFFC00" : "=v"(VMASK));

    f16x8 bfr[KS];
    #pragma unroll
    for (int ks = 0; ks < KS; ++ks)
        bfr[ks] = fxq8[((size_t)((b * TMAX + nt) * KS + ks)) * 64 + lane];

    f32x16 zvec = {};
    float b1 = 0.f, b2 = 0.f, b3 = 0.f, b4 = 0.f;

    f16x8 aA[KS], aB[KS];
    LDA(aA, 0);
    int t = 0;
    #pragma unroll 1
    for (; t + 1 < TPSr; t += 2) {
        LDA(aB, t + 1);
        CELL(aA, t);
        if (t + 2 < TPSr) LDA(aA, t + 2);
        CELL(aB, t + 1);
    }
    if (t < TPSr) CELL(aA, t);           // tail (TPSr odd)

    // candidates at COMPACTED row index: [b][n][split][hi][4]
    int n = nt * 32 + lo;
    size_t base = (((size_t)(b * N_ + n) * SPLIT + split) * 2 + hi) * LCAP;
    u32 pb0 = __float_as_uint(b1), pb1 = __float_as_uint(b2);
    u32 pb2 = __float_as_uint(b3), pb3 = __float_as_uint(b4);
    u32x4 pv = {pb0, pb1, pb2, pb3};
    u64 pidx = 0;
    u32 pbs[4] = {pb0, pb1, pb2, pb3};
    #pragma unroll
    for (int k = 0; k < 4; ++k) {
        int idx10 = (int)(pbs[k] & 1023u);
        int tl = idx10 >> 4, r = idx10 & 15;
        u32 mc = (u32)((tbase + tl) * 32 + (r & 3) + ((r >> 2) << 3) + (hi << 2));
        pidx |= (u64)(mc & 0xFFFFu) << (16 * k);
    }
    __builtin_nontemporal_store(pv, (u32x4*)&cvals[base]);
    __builtin_nontemporal_store(pidx, (u64*)&cidx[base]);
}

// ---------------------------------------------------------------------------
// Kernel 3: selective exact rescore over COMPACTED rows (maps back to
// original indices; bit-identical round-1 fp32 dot; tie: lower orig index).
// ---------------------------------------------------------------------------
__global__ __launch_bounds__(256)
void rescore(const u32* __restrict__ cvals, const u16* __restrict__ cidx,
             const float* __restrict__ fxT, const float* __restrict__ fynT,
             const float* __restrict__ nyeps, const float* __restrict__ minf,
             const int* __restrict__ cmapX, const int* __restrict__ cmapY,
             const int* __restrict__ hdr, float* __restrict__ out) {
    int gwf = blockIdx.x * 4 + (threadIdx.x >> 6);
    int lane = threadIdx.x & 63;
    int b = gwf / N_, slot = gwf - b * N_;
    if (slot >= hdr[4 + b]) return;
    int orig_n = cmapX[b * CMAPN + slot];

    float vn = __uint_as_float(cvals[(size_t)(b * N_ + slot) * CPR + lane]);
    int cm = cidx[(size_t)(b * N_ + slot) * CPR + lane];

    float cur = vn;
    float t3 = NEGINF;
    #pragma unroll
    for (int r = 0; r < 3; ++r) {
        float c = cur;
        #pragma unroll
        for (int off = 32; off >= 1; off >>= 1) c = fmaxf(c, __shfl_xor(c, off));
        t3 = c;
        cur = (cur == c) ? NEGINF : cur;
    }
    bool redo = (vn >= t3 - 0.125f);

    float rnk = NEGINF, wgt = 0.f;
    int midx = 0x7fffffff;
    if (redo) {
        int om = cmapY[b * CMAPN + cm];
        const float4* xq4 = (const float4*)(fxT + ((size_t)b * N_ + orig_n) * C_);
        const float4* fr4 = (const float4*)(fynT + ((size_t)b * N_ + om) * C_);
        float a = 0.f;
        #pragma unroll
        for (int c4 = 0; c4 < 16; ++c4) {
            float4 xf = xq4[c4];
            float4 f  = fr4[c4];
            a = fmaf(xf.x, f.x, a);
            a = fmaf(xf.y, f.y, a);
            a = fmaf(xf.z, f.z, a);
            a = fmaf(xf.w, f.w, a);
        }
        rnk = a + minf[(size_t)b * N_ + om];
        wgt = a * nyeps[(size_t)b * N_ + om];
        midx = om;
    }

    int wi[3]; float ww[3];
    #pragma unroll
    for (int r = 0; r < 3; ++r) {
        float cv = rnk; int ci = midx; float cw = wgt;
        #pragma unroll
        for (int off = 32; off >= 1; off >>= 1) {
            float ov = __shfl_xor(cv, off);
            int   oi = __shfl_xor(ci, off);
            float ow = __shfl_xor(cw, off);
            bool take = (ov > cv) || (ov == cv && oi < ci);
            cv = take ? ov : cv; ci = take ? oi : ci; cw = take ? ow : cw;
        }
        wi[r] = ci; ww[r] = cw;
        if (midx == ci) rnk = NEGINF;
    }

    if (lane == 0) {
        float w0 = ww[0], w1 = ww[1], w2 = ww[2];
        float h0 = (float)(wi[0] / W_), h1 = (float)(wi[1] / W_), h2 = (float)(wi[2] / W_);
        float q0 = (float)(wi[0] % W_), q1 = (float)(wi[1] % W_), q2 = (float)(wi[2] % W_);
        float den = w0 + w1 + w2;
        float ph = (h0 * w0 + h1 * w1 + h2 * w2) / den;
        float pw = (q0 * w0 + q1 * w1 + q2 * w2) / den;
        out[2 * ((size_t)b * N_ + orig_n)]     = ph;
        out[2 * ((size_t)b * N_ + orig_n) + 1] = pw;
    }
}

// ---------------------------------------------------------------------------
// Kernel 4: slic gather.
// ---------------------------------------------------------------------------
__global__ void slic_gather(const float* __restrict__ spg,
                            const float* __restrict__ pred,
                            float* __restrict__ outg) {
    int t = blockIdx.x * blockDim.x + threadIdx.x;
    if (t >= B_ * S_ * G_) return;
    int b = t / (S_ * G_);
    float vh = spg[2 * t], vw = spg[2 * t + 1];
    int ph = (int)rintf(vh * (float)H_);
    int pw = (int)rintf(vw * (float)H_);
    ph = ph < 0 ? 0 : (ph > H_ - 1 ? H_ - 1 : ph);
    pw = pw < 0 ? 0 : (pw > H_ - 1 ? H_ - 1 : pw);
    int lin = ph * W_ + pw;
    outg[2 * t]     = pred[((size_t)b * N_ + lin) * 2]     / (float)H_;
    outg[2 * t + 1] = pred[((size_t)b * N_ + lin) * 2 + 1] / (float)H_;
}

extern "C" void kernel_launch(void* const* d_in, const int* in_sizes, int n_in,
                              void* d_out, int out_size, void* d_ws, size_t ws_size,
                              hipStream_t stream) {
    const float* img1 = (const float*)d_in[0];
    const float* img2 = (const float*)d_in[1];
    const void*  mask1 = d_in[2];
    const void*  mask2 = d_in[3];
    const float* spg = (const float*)d_in[4];
    float* out = (float*)d_out;

    char* ws = (char*)d_ws;
    size_t off = 0;
    int*   hdr   = (int*)(ws + off);            off += 256;
    float* fynT  = (float*)(ws + off);          off += (size_t)B_ * N_ * C_ * 4;         // 6.42 MB
    float* fxT   = (float*)(ws + off);          off += (size_t)B_ * N_ * C_ * 4;         // 6.42 MB
    f16*   fxq   = (f16*)(ws + off);            off += (size_t)B_ * TMAX * KS * 64 * 16; // 4.1 MB
    f16*   fynq  = (f16*)(ws + off);            off += (size_t)B_ * TMAX * KS * 64 * 16; // 4.1 MB
    float* nyeps = (float*)(ws + off);          off += (size_t)B_ * N_ * 4;
    float* minf  = (float*)(ws + off);          off += (size_t)B_ * N_ * 4;
    int*   cmapY = (int*)(ws + off);            off += (size_t)B_ * CMAPN * 4;
    int*   cmapX = (int*)(ws + off);            off += (size_t)B_ * CMAPN * 4;
    int*   slotX = (int*)(ws + off);            off += (size_t)B_ * N_ * 4;
    int*   slotY = (int*)(ws + off);            off += (size_t)B_ * N_ * 4;
    u32*   cvals = (u32*)(ws + off);            off += (size_t)B_ * N_ * CPR * 4;        // 6.42 MB
    u16*   cidx  = (u16*)(ws + off);            off += (size_t)B_ * N_ * CPR * 2;        // 3.21 MB

    zerofill<<<1024, 256, 0, stream>>>((uint4*)fxq, (uint4*)fynq, cmapX, cmapY);
    scan_compact<<<4, 1024, 0, stream>>>((const unsigned char*)mask1,
                                         (const unsigned char*)mask2, hdr,
                                         slotX, slotY, cmapX, cmapY);
    dim3 gp((B_ * N_) / 256, 2);
    prep<<<gp, 256, 0, stream>>>(img1, img2, slotX, slotY,
                                 fxq, fxT, fynT, fynq, nyeps, minf, out);

    stage1<<<3200, 128, 0, stream>>>(fxq, fynq, hdr, cvals, cidx);

    rescore<<<(B_ * N_) / 4, 256, 0, stream>>>(
        cvals, cidx, fxT, fynT, nyeps, minf, cmapX, cmapY, hdr, out);

    slic_gather<<<(B_ * S_ * G_ + 255) / 256, 256, 0, stream>>>(
        spg, out, out + (size_t)B_ * N_ * 2);
}